// Round 3
// baseline (46034.647 us; speedup 1.0000x reference)
//
#include <hip/hip_runtime.h>

#define Bx 128
#define Sx 512
#define Fx 64
#define Hx 512
#define Xx 128   // 2F

// ---- workspace float offsets ----
#define PARTB_OFF 0ull                             // bwd Wout-partial [B][S][F]
#define H_OFF     ((size_t)Bx * Sx * Fx)           // 4,194,304
#define XH_OFF    (H_OFF + (size_t)2 * 2 * Bx * Hx)
#define BAR_OFF   (XH_OFF + (size_t)2 * Bx * Fx)   // 8 groups x 16 ints
#define FLAG_OFF  (BAR_OFF + 128)
#define XCC_OFF   (FLAG_OFF + 16)                  // 256 ints

// ---- LDS word offsets ----
#define LDSW_WHH   0
#define LDSW_XIN   26112                       // 3*16*8*68
#define LDSW_WRO   (LDSW_XIN + 32 * 160)
#define LDSW_WOUT  (LDSW_WRO + 2 * 544)
#define LDSW_TOTAL (LDSW_WOUT + 2 * 544 + 16)  // +pad; 33424 floats

struct BParams {
  const float* x; const void* mask;
  const float* Wih_f; const float* Whh_f; const float* bih_f; const float* bhh_f;
  const float* Wro_f; const float* bro_f;
  const float* Wih_b; const float* Whh_b; const float* bih_b; const float* bhh_b;
  const float* Wro_b; const float* bro_b;
  const float* Wout; const float* bout;
  float* out; float* ws;
};

__global__ void detect_kernel(const unsigned int* mask, float* ws) {
  int* bars = (int*)(ws + BAR_OFF);
  int* flag = (int*)(ws + FLAG_OFF);
  int t = threadIdx.x;
  if (t < 128) bars[t] = 0;
  if (t == 128) *flag = 0;
  __syncthreads();
  unsigned int v = 0;
  for (int i = t; i < 4096; i += blockDim.x) v |= mask[i] & 0xFFFFFF00u;
  if (v) atomicOr(flag, 1);
}

__global__ void combine_kernel(float* out, const float* partb, const float* bout) {
  int i = blockIdx.x * blockDim.x + threadIdx.x;
  out[i] = out[i] + partb[i] + bout[i & 63];
}

__device__ __forceinline__ void fma4(float& a, float4 w, float4 h) {
  a = fmaf(w.x, h.x, a); a = fmaf(w.y, h.y, a);
  a = fmaf(w.z, h.z, a); a = fmaf(w.w, h.w, a);
}

__device__ __forceinline__ float sel8(const float* a, int idx) {
  float v = a[0];
#pragma unroll
  for (int i = 1; i < 8; ++i) v = (idx == i) ? a[i] : v;
  return v;
}

// L0/L1-bypassing (sc0) 16B load via two agent-scope relaxed atomic b64 loads.
// Within one XCD, L2 is the coherence point: pairs with plain stores drained
// by the vmcnt(0) that __syncthreads emits before s_barrier.
__device__ __forceinline__ float4 ld4cg(const float* p) {
  unsigned long long a = __hip_atomic_load((const unsigned long long*)p,
                                           __ATOMIC_RELAXED, __HIP_MEMORY_SCOPE_AGENT);
  unsigned long long b = __hip_atomic_load((const unsigned long long*)(p + 2),
                                           __ATOMIC_RELAXED, __HIP_MEMORY_SCOPE_AGENT);
  float4 r;
  r.x = __uint_as_float((unsigned)(a & 0xffffffffu));
  r.y = __uint_as_float((unsigned)(a >> 32));
  r.z = __uint_as_float((unsigned)(b & 0xffffffffu));
  r.w = __uint_as_float((unsigned)(b >> 32));
  return r;
}

// 32-member barrier. fast=1: all members share an XCD/L2 -> relaxed counter,
// no wbl2/inv. fast=0: round-2 agent-scope release/acquire (any placement).
__device__ __forceinline__ void group_barrier(int* bar, int target, int fast) {
  __syncthreads();   // drains vmcnt(0): all waves' stores acked by L2
  if (threadIdx.x == 0) {
    if (fast) {
      __hip_atomic_fetch_add(bar, 1, __ATOMIC_RELAXED, __HIP_MEMORY_SCOPE_AGENT);
      while (__hip_atomic_load(bar, __ATOMIC_RELAXED, __HIP_MEMORY_SCOPE_AGENT) < target)
        __builtin_amdgcn_s_sleep(1);
    } else {
      __hip_atomic_fetch_add(bar, 1, __ATOMIC_RELEASE, __HIP_MEMORY_SCOPE_AGENT);
      while (__hip_atomic_load(bar, __ATOMIC_RELAXED, __HIP_MEMORY_SCOPE_AGENT) < target)
        __builtin_amdgcn_s_sleep(2);
      __threadfence();
    }
  }
  __syncthreads();
}

__global__ void __launch_bounds__(512, 2)
birnn_main(BParams p) {
  extern __shared__ float lds[];
  __shared__ int mode_sh;

  const int w   = blockIdx.x;
  const int g   = w & 7;         // group = (dir, batch-group); XCD candidate
  const int dir = g >> 2;
  const int bg  = g & 3;
  const int hs  = w >> 3;        // hidden slice 0..31
  const int b0  = bg * 32;
  const int u0  = hs * 16;
  const int f0  = hs * 2;
  const int tid = threadIdx.x;

  const float* Wih = dir ? p.Wih_b : p.Wih_f;
  const float* Whh = dir ? p.Whh_b : p.Whh_f;
  const float* bih = dir ? p.bih_b : p.bih_f;
  const float* bhh = dir ? p.bhh_b : p.bhh_f;
  const float* Wro = dir ? p.Wro_b : p.Wro_f;
  const float* bro = dir ? p.bro_b : p.bro_f;

  float* hbuf = p.ws + H_OFF;
  float* xhb  = p.ws + XH_OFF;
  int*   bar  = (int*)(p.ws + BAR_OFF) + g * 16;
  int*   xcc  = (int*)(p.ws + XCC_OFF);
  const int u8f = *(const int*)(p.ws + FLAG_OFF);
  const unsigned char* m8  = (const unsigned char*)p.mask;
  const int*           m32 = (const int*)p.mask;

  float* pout   = dir ? (p.ws + PARTB_OFF) : p.out;  // Wout half-partials
  float* out_xh = p.out + (size_t)(1 + dir) * Bx * Sx * Fx;

  // record this wg's XCC id (gfx950: HW_REG_XCC_ID, measured working)
  if (tid == 0) {
    unsigned xv;
    asm volatile("s_getreg_b32 %0, hwreg(HW_REG_XCC_ID)" : "=s"(xv));
    xcc[w] = (int)xv;
  }

  // ---- preload LDS-resident weight slices ----
  for (int idx = tid; idx < 3 * 16 * 512; idx += 512) {
    int g3 = idx >> 13; int rem = idx & 8191;
    int u = rem >> 9;   int j = rem & 511;
    lds[LDSW_WHH + ((g3 * 16 + u) * 8 + (j >> 6)) * 68 + (j & 63)] =
        Whh[(size_t)(g3 * 512 + u0 + u) * Hx + j];
  }
  for (int idx = tid; idx < 2 * 512; idx += 512) {
    int f = idx >> 9, j = idx & 511;
    lds[LDSW_WRO  + f * 544 + (j >> 6) * 68 + (j & 63)] = Wro[(size_t)(f0 + f) * Hx + j];
    lds[LDSW_WOUT + f * 544 + (j >> 6) * 68 + (j & 63)] =
        p.Wout[(size_t)(f0 + f) * (2 * Hx) + dir * Hx + j];
  }

  // ---- init: h=0, xhat=bro, boundary outputs ----
  if (hs == 0) {
    for (int idx = tid; idx < 32 * 512; idx += 512) {
      int b = b0 + (idx >> 9), j = idx & 511;
      hbuf[((size_t)(dir * 2 + 0) * Bx + b) * Hx + j] = 0.f;
    }
  }
  if (tid < 64) {
    int b = b0 + (tid >> 1), f = f0 + (tid & 1);
    float br = bro[f];
    xhb[((size_t)dir * Bx + b) * Fx + f] = br;
    int T0 = dir ? (Sx - 1) : 0;
    out_xh[((size_t)b * Sx + T0) * Fx + f] = br;
    pout  [((size_t)b * Sx + T0) * Fx + f] = 0.f;
  }

  // phase-A map: lane = jq(3b) x ulo(3b); wave = bsub(2b) x uhi(1b)
  const int jq   = tid & 7;
  const int ulo  = (tid >> 3) & 7;
  const int wv   = tid >> 6;
  const int bsub = wv & 3;
  const int uhi  = wv >> 2;
  const int u    = uhi * 8 + ulo;
  const int bA   = b0 + bsub * 8;
  const int ru   = u0 + u;
  // phase-B map: lane = jq(3b) x blo(3b); wave = bhi(2b) x fB(1b)
  const int blo  = (tid >> 3) & 7;
  const int bB   = b0 + (wv & 3) * 8 + blo;
  const int fB   = wv >> 2;

  // per-thread-invariant Wih rows + gate biases in registers
  float4 wih0[4], wih1[4], wih2[4];
#pragma unroll
  for (int q = 0; q < 4; ++q) {
    wih0[q] = *(const float4*)(Wih + (size_t)(0 * 512 + ru) * Xx + jq * 16 + q * 4);
    wih1[q] = *(const float4*)(Wih + (size_t)(1 * 512 + ru) * Xx + jq * 16 + q * 4);
    wih2[q] = *(const float4*)(Wih + (size_t)(2 * 512 + ru) * Xx + jq * 16 + q * 4);
  }
  const float bs_r = bih[ru] + bhh[ru];
  const float bs_z = bih[512 + ru] + bhh[512 + ru];
  const float bs_i = bih[1024 + ru];
  const float bs_h = bhh[1024 + ru];

  const float* w0p = lds + LDSW_WHH + ((0 * 16 + u) * 8 + jq) * 68;
  const float* w1p = lds + LDSW_WHH + ((1 * 16 + u) * 8 + jq) * 68;
  const float* w2p = lds + LDSW_WHH + ((2 * 16 + u) * 8 + jq) * 68;

  // own h value (batch bA+jq, unit ru) is written by THIS thread every step
  float hprev_own = 0.f;

  int bt = 32;
  group_barrier(bar, bt, 0);   // publish init + xcc (agent scope)

  // decide barrier mode: fast iff all 32 members report the same XCC
  if (tid == 0) {
    int ref = __hip_atomic_load(&xcc[g], __ATOMIC_RELAXED, __HIP_MEMORY_SCOPE_AGENT);
    int ok = 1;
    for (int i = 1; i < 32; ++i) {
      int v = __hip_atomic_load(&xcc[g + 8 * i], __ATOMIC_RELAXED, __HIP_MEMORY_SCOPE_AGENT);
      ok &= (v == ref);
    }
    mode_sh = ok;
  }
  __syncthreads();
  const int fast = mode_sh;

  for (int k = 1; k < Sx; ++k) {
    const int pp = k & 1, pr = pp ^ 1;
    const int t_in = dir ? (Sx - k) : (k - 1);

    // ---- stage x_in = [x_p, m] into LDS (vectorized) ----
    {
      int bl = tid >> 4, sub = tid & 15;
      int b = b0 + bl;
      float* xr = lds + LDSW_XIN + bl * 160 + (sub >> 1) * 20 + (sub & 1) * 8;
      float v[8];
      if (sub < 8) {
        size_t base = ((size_t)b * Sx + t_in) * Fx + sub * 8;
        float4 xa = *(const float4*)(p.x + base);
        float4 xb = *(const float4*)(p.x + base + 4);
        const float* xhp = xhb + ((size_t)dir * Bx + b) * Fx + sub * 8;
        float4 ha = ld4cg(xhp);
        float4 hb4 = ld4cg(xhp + 4);
        int mi[8];
        if (u8f) {
          unsigned long long mm = *(const unsigned long long*)(m8 + base);
#pragma unroll
          for (int j = 0; j < 8; ++j) mi[j] = (int)((mm >> (8 * j)) & 0xFF);
        } else {
          int4 ma = *(const int4*)(m32 + base);
          int4 mb = *(const int4*)(m32 + base + 4);
          mi[0] = ma.x; mi[1] = ma.y; mi[2] = ma.z; mi[3] = ma.w;
          mi[4] = mb.x; mi[5] = mb.y; mi[6] = mb.z; mi[7] = mb.w;
        }
        v[0] = mi[0] ? xa.x : ha.x;  v[1] = mi[1] ? xa.y : ha.y;
        v[2] = mi[2] ? xa.z : ha.z;  v[3] = mi[3] ? xa.w : ha.w;
        v[4] = mi[4] ? xb.x : hb4.x; v[5] = mi[5] ? xb.y : hb4.y;
        v[6] = mi[6] ? xb.z : hb4.z; v[7] = mi[7] ? xb.w : hb4.w;
      } else {
        size_t base = ((size_t)b * Sx + t_in) * Fx + (sub - 8) * 8;
        if (u8f) {
          unsigned long long mm = *(const unsigned long long*)(m8 + base);
#pragma unroll
          for (int j = 0; j < 8; ++j) v[j] = (float)((mm >> (8 * j)) & 0xFF);
        } else {
          int4 ma = *(const int4*)(m32 + base);
          int4 mb = *(const int4*)(m32 + base + 4);
          v[0] = (float)ma.x; v[1] = (float)ma.y; v[2] = (float)ma.z; v[3] = (float)ma.w;
          v[4] = (float)mb.x; v[5] = (float)mb.y; v[6] = (float)mb.z; v[7] = (float)mb.w;
        }
      }
      *(float4*)(xr)     = make_float4(v[0], v[1], v[2], v[3]);
      *(float4*)(xr + 4) = make_float4(v[4], v[5], v[6], v[7]);
    }
    __syncthreads();

    float acc0[8], acc1[8], acc2[8], acc3[8];
#pragma unroll
    for (int i = 0; i < 8; ++i) { acc0[i] = 0.f; acc1[i] = 0.f; acc2[i] = 0.f; acc3[i] = 0.f; }

    // ---- gh: Whh slice (LDS) x h_prev (L2, sc0) ----
    {
      const float* hrd = hbuf + (size_t)(dir * 2 + pr) * Bx * Hx;
      const int j0 = jq * 64;
#pragma unroll 2
      for (int jj = 0; jj < 64; jj += 4) {
        float4 w0 = *(const float4*)(w0p + jj);
        float4 w1 = *(const float4*)(w1p + jj);
        float4 w2 = *(const float4*)(w2p + jj);
#pragma unroll
        for (int bb = 0; bb < 8; ++bb) {
          float4 h4 = ld4cg(hrd + (size_t)(bA + bb) * Hx + j0 + jj);
          fma4(acc0[bb], w0, h4);
          fma4(acc1[bb], w1, h4);
          fma4(acc3[bb], w2, h4);
        }
      }
    }
    // ---- gi: Wih rows (registers) x x_in (LDS) ----
    {
      const float* xinb = lds + LDSW_XIN;
#pragma unroll
      for (int q = 0; q < 4; ++q) {
        float4 w0 = wih0[q], w1 = wih1[q], w2 = wih2[q];
        int off = jq * 20 + q * 4;
#pragma unroll
        for (int bb = 0; bb < 8; ++bb) {
          float4 xv = *(const float4*)(xinb + (bsub * 8 + bb) * 160 + off);
          fma4(acc0[bb], w0, xv);
          fma4(acc1[bb], w1, xv);
          fma4(acc2[bb], w2, xv);
        }
      }
    }
    // ---- reduce across jq ----
#pragma unroll
    for (int m = 1; m <= 4; m <<= 1) {
#pragma unroll
      for (int bb = 0; bb < 8; ++bb) {
        acc0[bb] += __shfl_xor(acc0[bb], m);
        acc1[bb] += __shfl_xor(acc1[bb], m);
        acc2[bb] += __shfl_xor(acc2[bb], m);
        acc3[bb] += __shfl_xor(acc3[bb], m);
      }
    }
    // ---- gates: lane jq handles batch bA+jq; h_prev from register ----
    {
      int b = bA + jq;
      float sr  = sel8(acc0, jq);
      float sz  = sel8(acc1, jq);
      float sgi = sel8(acc2, jq);
      float sgh = sel8(acc3, jq);
      float r = 1.f / (1.f + __expf(-(sr + bs_r)));
      float z = 1.f / (1.f + __expf(-(sz + bs_z)));
      float n = tanhf(sgi + bs_i + r * (sgh + bs_h));
      float hn = (1.f - z) * n + z * hprev_own;
      hprev_own = hn;
      hbuf[(size_t)(dir * 2 + pp) * Bx * Hx + (size_t)b * Hx + ru] = hn;
    }
    bt += 32;
    group_barrier(bar, bt, fast);   // h_new visible to group

    // ---- phase B: xhat = Wro@h + bro ; Wout-half partial ----
    {
      const float* hnw  = hbuf + (size_t)(dir * 2 + pp) * Bx * Hx;
      const float* wroL = lds + LDSW_WRO  + fB * 544 + jq * 68;
      const float* wouL = lds + LDSW_WOUT + fB * 544 + jq * 68;
      const float* hb   = hnw + (size_t)bB * Hx + jq * 64;
      float ax = 0.f, ap = 0.f;
#pragma unroll 2
      for (int jj = 0; jj < 64; jj += 4) {
        float4 h4 = ld4cg(hb + jj);
        float4 wx = *(const float4*)(wroL + jj);
        float4 wp = *(const float4*)(wouL + jj);
        fma4(ax, wx, h4);
        fma4(ap, wp, h4);
      }
#pragma unroll
      for (int m = 1; m <= 4; m <<= 1) {
        ax += __shfl_xor(ax, m);
        ap += __shfl_xor(ap, m);
      }
      const int T = dir ? (Sx - 1 - k) : k;
      const int f = f0 + fB;
      if (jq == 0) {
        float v = ax + bro[f];
        xhb[((size_t)dir * Bx + bB) * Fx + f] = v;
        out_xh[((size_t)bB * Sx + T) * Fx + f] = v;
      } else if (jq == 1) {
        pout[((size_t)bB * Sx + T) * Fx + f] = ap;   // pure write, no RMW
      }
    }
    bt += 32;
    group_barrier(bar, bt, fast);   // xhb visible for next staging
  }
}

extern "C" void kernel_launch(void* const* d_in, const int* in_sizes, int n_in,
                              void* d_out, int out_size, void* d_ws, size_t ws_size,
                              hipStream_t stream) {
  (void)in_sizes; (void)n_in; (void)out_size; (void)ws_size;
  float* ws = (float*)d_ws;

  detect_kernel<<<1, 256, 0, stream>>>((const unsigned int*)d_in[1], ws);

  BParams p;
  p.x     = (const float*)d_in[0];  p.mask = d_in[1];
  p.Wih_f = (const float*)d_in[2];  p.Whh_f = (const float*)d_in[3];
  p.bih_f = (const float*)d_in[4];  p.bhh_f = (const float*)d_in[5];
  p.Wro_f = (const float*)d_in[6];  p.bro_f = (const float*)d_in[7];
  p.Wih_b = (const float*)d_in[8];  p.Whh_b = (const float*)d_in[9];
  p.bih_b = (const float*)d_in[10]; p.bhh_b = (const float*)d_in[11];
  p.Wro_b = (const float*)d_in[12]; p.bro_b = (const float*)d_in[13];
  p.Wout  = (const float*)d_in[14]; p.bout  = (const float*)d_in[15];
  p.out   = (float*)d_out;
  p.ws    = ws;

  hipFuncSetAttribute(reinterpret_cast<const void*>(birnn_main),
                      hipFuncAttributeMaxDynamicSharedMemorySize,
                      (int)(LDSW_TOTAL * sizeof(float)));
  void* args[] = { (void*)&p };
  hipLaunchCooperativeKernel(reinterpret_cast<void*>(birnn_main),
                             dim3(256), dim3(512), args,
                             (unsigned)(LDSW_TOTAL * sizeof(float)), stream);

  combine_kernel<<<dim3(Bx * Sx * Fx / 256), dim3(256), 0, stream>>>(
      (float*)d_out, ws + PARTB_OFF, (const float*)d_in[15]);
}

// Round 5
// 24583.151 us; speedup vs baseline: 1.8726x; 1.8726x over previous
//
#include <hip/hip_runtime.h>

#define Bx 128
#define Sx 512
#define Fx 64
#define Hx 512
#define Xx 128   // 2F

// ---- workspace float offsets ----
#define PARTB_OFF 0ull                             // bwd Wout-partial [B][S][F]
#define H_OFF     ((size_t)Bx * Sx * Fx)           // 4,194,304
#define XH_OFF    (H_OFF + (size_t)2 * 2 * Bx * Hx)
#define BAR_OFF   (XH_OFF + (size_t)2 * Bx * Fx)   // 2624 ints, layout below
#define FLAG_OFF  (BAR_OFF + 2624)
#define XCC_OFF   (FLAG_OFF + 16)                  // 256 ints

// bar layout (ints): grid ctr @0 (64 reserved) | slow ctrs @64+g*64 (256B apart)
//                    fast slots @576+g*256+rank (1024B per group, line-isolated)
#define BAR_GRID   0
#define BAR_SLOW   64
#define BAR_FSLOT  576
#define BAR_TOTAL  2624

// ---- LDS word offsets ----
#define LDSW_WHH   0
#define LDSW_XIN   26112                       // 3*16*8*68
#define LDSW_WRO   (LDSW_XIN + 32 * 160)
#define LDSW_WOUT  (LDSW_WRO + 2 * 544)
#define LDSW_TOTAL (LDSW_WOUT + 2 * 544 + 16)  // 33424 floats -> 1 wg/CU

struct BParams {
  const float* x; const void* mask;
  const float* Wih_f; const float* Whh_f; const float* bih_f; const float* bhh_f;
  const float* Wro_f; const float* bro_f;
  const float* Wih_b; const float* Whh_b; const float* bih_b; const float* bhh_b;
  const float* Wro_b; const float* bro_b;
  const float* Wout; const float* bout;
  float* out; float* ws;
};

__global__ void detect_kernel(const unsigned int* mask, float* ws) {
  int* bars = (int*)(ws + BAR_OFF);
  int* flag = (int*)(ws + FLAG_OFF);
  int t = threadIdx.x;
  for (int i = t; i < BAR_TOTAL; i += blockDim.x) bars[i] = 0;
  if (t == 0) *flag = 0;
  __syncthreads();
  unsigned int v = 0;
  for (int i = t; i < 4096; i += blockDim.x) v |= mask[i] & 0xFFFFFF00u;
  if (v) atomicOr(flag, 1);
}

__global__ void combine_kernel(float* out, const float* partb, const float* bout) {
  int i = blockIdx.x * blockDim.x + threadIdx.x;
  out[i] = out[i] + partb[i] + bout[i & 63];
}

__device__ __forceinline__ void fma4(float& a, float4 w, float4 h) {
  a = fmaf(w.x, h.x, a); a = fmaf(w.y, h.y, a);
  a = fmaf(w.z, h.z, a); a = fmaf(w.w, h.w, a);
}

__device__ __forceinline__ float sel8(const float* a, int idx) {
  float v = a[0];
#pragma unroll
  for (int i = 1; i < 8; ++i) v = (idx == i) ? a[i] : v;
  return v;
}

// 32-member barrier, ordinal nbar (monotonic).
// fast=1 (all members verified on ONE XCD): entry __syncthreads drains every
// wave's stores into the shared L2 (vmcnt-ack => committed in L2: proven by
// round-2's wbl2 protocol flushing exactly those stores). Arrival is a slot
// STORE at agent scope (write-through to fabric, no RMW contention); wave 0
// polls all 32 slots in parallel; one bare buffer_inv invalidates the
// (write-through, never dirty) vector L1 so subsequent plain loads refill
// from the fresh shared L2. No wbl2, no L2 invalidate.
// fast=0: round-2 proven agent release/acquire protocol.
__device__ __forceinline__ void gbar(int fast, int* fslots, int rank,
                                     int* sctr, int nbar) {
  __syncthreads();
  if (fast) {
    if (threadIdx.x == 0)
      __hip_atomic_store(fslots + rank, nbar, __ATOMIC_RELAXED,
                         __HIP_MEMORY_SCOPE_AGENT);
    if (threadIdx.x < 64) {
      const int lane = threadIdx.x & 31;   // both half-waves poll slots 0..31
      for (;;) {
        int v = __hip_atomic_load(fslots + lane, __ATOMIC_RELAXED,
                                  __HIP_MEMORY_SCOPE_AGENT);
        if (__all(v >= nbar)) break;
        __builtin_amdgcn_s_sleep(1);
      }
      asm volatile("buffer_inv" ::: "memory");
    }
  } else {
    if (threadIdx.x == 0) {
      __hip_atomic_fetch_add(sctr, 1, __ATOMIC_RELEASE, __HIP_MEMORY_SCOPE_AGENT);
      while (__hip_atomic_load(sctr, __ATOMIC_RELAXED, __HIP_MEMORY_SCOPE_AGENT)
             < nbar * 32)
        __builtin_amdgcn_s_sleep(2);
      __threadfence();
    }
  }
  __syncthreads();
}

__global__ void __launch_bounds__(512, 2)
birnn_main(BParams p) {
  extern __shared__ float lds[];
  __shared__ int sh_fast, sh_g, sh_slice;

  const int w   = blockIdx.x;
  const int tid = threadIdx.x;

  float* hbuf = p.ws + H_OFF;
  float* xhb  = p.ws + XH_OFF;
  int*   bars = (int*)(p.ws + BAR_OFF);
  int*   xcc  = (int*)(p.ws + XCC_OFF);
  const int u8f = *(const int*)(p.ws + FLAG_OFF);
  const unsigned char* m8  = (const unsigned char*)p.mask;
  const int*           m32 = (const int*)p.mask;

  // 1) record this wg's physical XCD
  if (tid == 0) {
    unsigned xv;
    asm volatile("s_getreg_b32 %0, hwreg(HW_REG_XCC_ID)" : "=s"(xv));
    xcc[w] = (int)xv;
  }
  // 2) one agent-scope grid barrier to publish xcc (proven protocol)
  __syncthreads();
  if (tid == 0) {
    int* gb = bars + BAR_GRID;
    __hip_atomic_fetch_add(gb, 1, __ATOMIC_RELEASE, __HIP_MEMORY_SCOPE_AGENT);
    while (__hip_atomic_load(gb, __ATOMIC_RELAXED, __HIP_MEMORY_SCOPE_AGENT) < 256)
      __builtin_amdgcn_s_sleep(4);
    __threadfence();
  }
  __syncthreads();
  // 3) adaptive roles: group = physical XCD, slice = rank within it.
  //    fast only if every XCD hosts exactly 32 wgs (1 wg/CU via 133KB LDS).
  if (tid == 0) {
    int myx = xcc[w];
    int cnt[8] = {0,0,0,0,0,0,0,0};
    int rank = 0, bad = 0;
    for (int i = 0; i < 256; ++i) {
      int xi = xcc[i];
      if (xi < 0 || xi > 7) { bad = 1; break; }
      cnt[xi]++;
      if (i < w && xi == myx) rank++;
    }
    int ok = !bad;
    if (!bad)
      for (int c = 0; c < 8; ++c) ok &= (cnt[c] == 32);
    sh_fast  = ok;
    sh_g     = ok ? myx : (w & 7);
    sh_slice = ok ? rank : (w >> 3);
  }
  __syncthreads();
  const int fast = sh_fast;
  const int g    = sh_g;          // group = (dir, batch-group)
  const int hs   = sh_slice;      // hidden slice 0..31 (= slot rank)
  const int dir  = g >> 2;
  const int bg   = g & 3;
  const int b0   = bg * 32;
  const int u0   = hs * 16;
  const int f0   = hs * 2;
  int* fslots = bars + BAR_FSLOT + g * 256;
  int* sctr   = bars + BAR_SLOW  + g * 64;

  const float* Wih = dir ? p.Wih_b : p.Wih_f;
  const float* Whh = dir ? p.Whh_b : p.Whh_f;
  const float* bih = dir ? p.bih_b : p.bih_f;
  const float* bhh = dir ? p.bhh_b : p.bhh_f;
  const float* Wro = dir ? p.Wro_b : p.Wro_f;
  const float* bro = dir ? p.bro_b : p.bro_f;

  float* pout   = dir ? (p.ws + PARTB_OFF) : p.out;  // Wout half-partials
  float* out_xh = p.out + (size_t)(1 + dir) * Bx * Sx * Fx;

  // ---- preload LDS-resident weight slices ----
  for (int idx = tid; idx < 3 * 16 * 512; idx += 512) {
    int g3 = idx >> 13; int rem = idx & 8191;
    int u = rem >> 9;   int j = rem & 511;
    lds[LDSW_WHH + ((g3 * 16 + u) * 8 + (j >> 6)) * 68 + (j & 63)] =
        Whh[(size_t)(g3 * 512 + u0 + u) * Hx + j];
  }
  for (int idx = tid; idx < 2 * 512; idx += 512) {
    int f = idx >> 9, j = idx & 511;
    lds[LDSW_WRO  + f * 544 + (j >> 6) * 68 + (j & 63)] = Wro[(size_t)(f0 + f) * Hx + j];
    lds[LDSW_WOUT + f * 544 + (j >> 6) * 68 + (j & 63)] =
        p.Wout[(size_t)(f0 + f) * (2 * Hx) + dir * Hx + j];
  }

  // ---- init: h=0, xhat=bro, boundary outputs ----
  if (hs == 0) {
    for (int idx = tid; idx < 32 * 512; idx += 512) {
      int b = b0 + (idx >> 9), j = idx & 511;
      hbuf[((size_t)(dir * 2 + 0) * Bx + b) * Hx + j] = 0.f;
    }
  }
  if (tid < 64) {
    int b = b0 + (tid >> 1), f = f0 + (tid & 1);
    float br = bro[f];
    xhb[((size_t)dir * Bx + b) * Fx + f] = br;
    int T0 = dir ? (Sx - 1) : 0;
    out_xh[((size_t)b * Sx + T0) * Fx + f] = br;
    pout  [((size_t)b * Sx + T0) * Fx + f] = 0.f;
  }

  // phase-A map: lane = jq(3b) x ulo(3b); wave = bsub(2b) x uhi(1b)
  const int jq   = tid & 7;
  const int ulo  = (tid >> 3) & 7;
  const int wv   = tid >> 6;
  const int bsub = wv & 3;
  const int uhi  = wv >> 2;
  const int u    = uhi * 8 + ulo;
  const int bA   = b0 + bsub * 8;
  const int ru   = u0 + u;
  const int j0   = jq * 64;
  // phase-B map: lane = jq(3b) x blo(3b); wave = bhi(2b) x fB(1b)
  const int blo  = (tid >> 3) & 7;
  const int bB   = b0 + (wv & 3) * 8 + blo;
  const int fB   = wv >> 2;

  // per-thread-invariant Wih rows + gate biases in registers
  float4 wih0[4], wih1[4], wih2[4];
#pragma unroll
  for (int q = 0; q < 4; ++q) {
    wih0[q] = *(const float4*)(Wih + (size_t)(0 * 512 + ru) * Xx + jq * 16 + q * 4);
    wih1[q] = *(const float4*)(Wih + (size_t)(1 * 512 + ru) * Xx + jq * 16 + q * 4);
    wih2[q] = *(const float4*)(Wih + (size_t)(2 * 512 + ru) * Xx + jq * 16 + q * 4);
  }
  const float bs_r = bih[ru] + bhh[ru];
  const float bs_z = bih[512 + ru] + bhh[512 + ru];
  const float bs_i = bih[1024 + ru];
  const float bs_h = bhh[1024 + ru];

  const float* w0p = lds + LDSW_WHH + ((0 * 16 + u) * 8 + jq) * 68;
  const float* w1p = lds + LDSW_WHH + ((1 * 16 + u) * 8 + jq) * 68;
  const float* w2p = lds + LDSW_WHH + ((2 * 16 + u) * 8 + jq) * 68;

  float hprev_own = 0.f;   // h[bA+jq][ru], written by this thread every step

  int nbar = 1;
  gbar(fast, fslots, hs, sctr, nbar);   // publish init

  for (int k = 1; k < Sx; ++k) {
    const int pp = k & 1, pr = pp ^ 1;
    const int t_in = dir ? (Sx - k) : (k - 1);

    // ---- stage x_in = [x_p, m] into LDS (vectorized, plain loads) ----
    {
      int bl = tid >> 4, sub = tid & 15;
      int b = b0 + bl;
      float* xr = lds + LDSW_XIN + bl * 160 + (sub >> 1) * 20 + (sub & 1) * 8;
      float v[8];
      if (sub < 8) {
        size_t base = ((size_t)b * Sx + t_in) * Fx + sub * 8;
        float4 xa = *(const float4*)(p.x + base);
        float4 xb = *(const float4*)(p.x + base + 4);
        const float* xhp = xhb + ((size_t)dir * Bx + b) * Fx + sub * 8;
        float4 ha  = *(const float4*)(xhp);
        float4 hb4 = *(const float4*)(xhp + 4);
        int mi[8];
        if (u8f) {
          unsigned long long mm = *(const unsigned long long*)(m8 + base);
#pragma unroll
          for (int j = 0; j < 8; ++j) mi[j] = (int)((mm >> (8 * j)) & 0xFF);
        } else {
          int4 ma = *(const int4*)(m32 + base);
          int4 mb = *(const int4*)(m32 + base + 4);
          mi[0] = ma.x; mi[1] = ma.y; mi[2] = ma.z; mi[3] = ma.w;
          mi[4] = mb.x; mi[5] = mb.y; mi[6] = mb.z; mi[7] = mb.w;
        }
        v[0] = mi[0] ? xa.x : ha.x;  v[1] = mi[1] ? xa.y : ha.y;
        v[2] = mi[2] ? xa.z : ha.z;  v[3] = mi[3] ? xa.w : ha.w;
        v[4] = mi[4] ? xb.x : hb4.x; v[5] = mi[5] ? xb.y : hb4.y;
        v[6] = mi[6] ? xb.z : hb4.z; v[7] = mi[7] ? xb.w : hb4.w;
      } else {
        size_t base = ((size_t)b * Sx + t_in) * Fx + (sub - 8) * 8;
        if (u8f) {
          unsigned long long mm = *(const unsigned long long*)(m8 + base);
#pragma unroll
          for (int j = 0; j < 8; ++j) v[j] = (float)((mm >> (8 * j)) & 0xFF);
        } else {
          int4 ma = *(const int4*)(m32 + base);
          int4 mb = *(const int4*)(m32 + base + 4);
          v[0] = (float)ma.x; v[1] = (float)ma.y; v[2] = (float)ma.z; v[3] = (float)ma.w;
          v[4] = (float)mb.x; v[5] = (float)mb.y; v[6] = (float)mb.z; v[7] = (float)mb.w;
        }
      }
      *(float4*)(xr)     = make_float4(v[0], v[1], v[2], v[3]);
      *(float4*)(xr + 4) = make_float4(v[4], v[5], v[6], v[7]);
    }
    __syncthreads();

    float acc0[8], acc1[8], acc2[8], acc3[8];
#pragma unroll
    for (int i = 0; i < 8; ++i) { acc0[i] = 0.f; acc1[i] = 0.f; acc2[i] = 0.f; acc3[i] = 0.f; }

    // ---- gh: Whh slice (LDS) x h_prev (plain cached loads; fresh via inv) ----
    {
      const float* hrd = hbuf + (size_t)(dir * 2 + pr) * Bx * Hx;
#pragma unroll 2
      for (int jj = 0; jj < 64; jj += 4) {
        float4 w0 = *(const float4*)(w0p + jj);
        float4 w1 = *(const float4*)(w1p + jj);
        float4 w2 = *(const float4*)(w2p + jj);
#pragma unroll
        for (int bb = 0; bb < 8; ++bb) {
          float4 h4 = *(const float4*)(hrd + (size_t)(bA + bb) * Hx + j0 + jj);
          fma4(acc0[bb], w0, h4);
          fma4(acc1[bb], w1, h4);
          fma4(acc3[bb], w2, h4);
        }
      }
    }
    // ---- gi: Wih rows (registers) x x_in (LDS) ----
    {
      const float* xinb = lds + LDSW_XIN;
#pragma unroll
      for (int q = 0; q < 4; ++q) {
        float4 w0 = wih0[q], w1 = wih1[q], w2 = wih2[q];
        int off = jq * 20 + q * 4;
#pragma unroll
        for (int bb = 0; bb < 8; ++bb) {
          float4 xv = *(const float4*)(xinb + (bsub * 8 + bb) * 160 + off);
          fma4(acc0[bb], w0, xv);
          fma4(acc1[bb], w1, xv);
          fma4(acc2[bb], w2, xv);
        }
      }
    }
    // ---- reduce across jq ----
#pragma unroll
    for (int m = 1; m <= 4; m <<= 1) {
#pragma unroll
      for (int bb = 0; bb < 8; ++bb) {
        acc0[bb] += __shfl_xor(acc0[bb], m);
        acc1[bb] += __shfl_xor(acc1[bb], m);
        acc2[bb] += __shfl_xor(acc2[bb], m);
        acc3[bb] += __shfl_xor(acc3[bb], m);
      }
    }
    // ---- gates: lane jq handles batch bA+jq; h_prev from register ----
    {
      int b = bA + jq;
      float sr  = sel8(acc0, jq);
      float sz  = sel8(acc1, jq);
      float sgi = sel8(acc2, jq);
      float sgh = sel8(acc3, jq);
      float r = 1.f / (1.f + __expf(-(sr + bs_r)));
      float z = 1.f / (1.f + __expf(-(sz + bs_z)));
      float n = tanhf(sgi + bs_i + r * (sgh + bs_h));
      float hn = (1.f - z) * n + z * hprev_own;
      hprev_own = hn;
      hbuf[(size_t)(dir * 2 + pp) * Bx * Hx + (size_t)b * Hx + ru] = hn;
    }
    ++nbar;
    gbar(fast, fslots, hs, sctr, nbar);   // h_new visible to group

    // ---- phase B: xhat = Wro@h + bro ; Wout-half partial ----
    {
      const float* hnw  = hbuf + (size_t)(dir * 2 + pp) * Bx * Hx;
      const float* wroL = lds + LDSW_WRO  + fB * 544 + jq * 68;
      const float* wouL = lds + LDSW_WOUT + fB * 544 + jq * 68;
      const float* hb   = hnw + (size_t)bB * Hx + jq * 64;
      float ax = 0.f, ap = 0.f;
#pragma unroll 2
      for (int jj = 0; jj < 64; jj += 4) {
        float4 h4 = *(const float4*)(hb + jj);
        float4 wx = *(const float4*)(wroL + jj);
        float4 wp = *(const float4*)(wouL + jj);
        fma4(ax, wx, h4);
        fma4(ap, wp, h4);
      }
#pragma unroll
      for (int m = 1; m <= 4; m <<= 1) {
        ax += __shfl_xor(ax, m);
        ap += __shfl_xor(ap, m);
      }
      const int T = dir ? (Sx - 1 - k) : k;
      const int f = f0 + fB;
      if (jq == 0) {
        float v = ax + bro[f];
        xhb[((size_t)dir * Bx + bB) * Fx + f] = v;
        out_xh[((size_t)bB * Sx + T) * Fx + f] = v;
      } else if (jq == 1) {
        pout[((size_t)bB * Sx + T) * Fx + f] = ap;   // pure write, no RMW
      }
    }
    ++nbar;
    gbar(fast, fslots, hs, sctr, nbar);   // xhb visible for next staging
  }
}

extern "C" void kernel_launch(void* const* d_in, const int* in_sizes, int n_in,
                              void* d_out, int out_size, void* d_ws, size_t ws_size,
                              hipStream_t stream) {
  (void)in_sizes; (void)n_in; (void)out_size; (void)ws_size;
  float* ws = (float*)d_ws;

  detect_kernel<<<1, 512, 0, stream>>>((const unsigned int*)d_in[1], ws);

  BParams p;
  p.x     = (const float*)d_in[0];  p.mask = d_in[1];
  p.Wih_f = (const float*)d_in[2];  p.Whh_f = (const float*)d_in[3];
  p.bih_f = (const float*)d_in[4];  p.bhh_f = (const float*)d_in[5];
  p.Wro_f = (const float*)d_in[6];  p.bro_f = (const float*)d_in[7];
  p.Wih_b = (const float*)d_in[8];  p.Whh_b = (const float*)d_in[9];
  p.bih_b = (const float*)d_in[10]; p.bhh_b = (const float*)d_in[11];
  p.Wro_b = (const float*)d_in[12]; p.bro_b = (const float*)d_in[13];
  p.Wout  = (const float*)d_in[14]; p.bout  = (const float*)d_in[15];
  p.out   = (float*)d_out;
  p.ws    = ws;

  hipFuncSetAttribute(reinterpret_cast<const void*>(birnn_main),
                      hipFuncAttributeMaxDynamicSharedMemorySize,
                      (int)(LDSW_TOTAL * sizeof(float)));
  void* args[] = { (void*)&p };
  hipLaunchCooperativeKernel(reinterpret_cast<void*>(birnn_main),
                             dim3(256), dim3(512), args,
                             (unsigned)(LDSW_TOTAL * sizeof(float)), stream);

  combine_kernel<<<dim3(Bx * Sx * Fx / 256), dim3(256), 0, stream>>>(
      (float*)d_out, ws + PARTB_OFF, (const float*)d_in[15]);
}